// Round 5
// baseline (82.986 us; speedup 1.0000x reference)
//
#include <hip/hip_runtime.h>

// FeatureLayer: out[row] = concat( sum_k W_item[item_hist[row,k]],        (64)
//                                  mean_k W_cate[cate_hist[row,k]],       (64)
//                                  concat_k W_ctx[ctx_ids[row,k]],        (640)
//                                  price[row],                            (1)
//                                  dense_vec[row] )                       (128)
// padding_idx = 0: index 0 contributes zeros. Mean divides by L=50 incl. padding.
//
// Strategy: one wave per row. Issue EVERY load the row needs back-to-back
// (26 table-row gathers + 10 ctx + 2 dense + price), then a
// sched_barrier(0) fence so the scheduler cannot sink loads to their uses.
// This forces ~26 outstanding table-row misses per wave (VGPR ~150) instead
// of the ~4 the default schedule achieves (VGPR 36) — trading occupancy for
// memory-level parallelism on a latency-bound gather.

#define LH 50      // item/cate history length
#define LC 20      // ctx length
#define DI 64      // item emb dim
#define DC 64      // cate emb dim
#define DX 32      // ctx emb dim
#define DDENSE 128
#define OUT_D 897  // 64 + 64 + 640 + 1 + 128
#define NIT 13     // ceil(LH/4)

typedef float f32x4 __attribute__((ext_vector_type(4)));

__global__ __launch_bounds__(256) void featlayer_kernel(
    const int* __restrict__ item_hist,
    const int* __restrict__ cate_hist,
    const int* __restrict__ ctx_ids,
    const float* __restrict__ price,
    const float* __restrict__ dense_vec,
    const float* __restrict__ W_item,
    const float* __restrict__ W_cate,
    const float* __restrict__ W_ctx,
    float* __restrict__ out,
    int B)
{
    const int wave = threadIdx.x >> 6;
    const int lane = threadIdx.x & 63;
    const int row  = blockIdx.x * 4 + wave;
    if (row >= B) return;

    const int sub = lane >> 4;   // 0..3 : which index within a group of 4
    const int l16 = lane & 15;   // 0..15: which float4 of the 64-wide emb row

    float* __restrict__ orow = out + (size_t)row * OUT_D;

    // ---- phase 0: index loads (must complete before gathers can issue) ----
    const int* __restrict__ ih = item_hist + row * LH;
    const int* __restrict__ ch = cate_hist + row * LH;
    const int* __restrict__ cids = ctx_ids + row * LC;

    int idxI[NIT], idxC[NIT];
    #pragma unroll
    for (int k = 0; k < NIT; ++k) {
        const int ki = sub + 4 * k;
        idxI[k] = (ki < LH) ? ih[ki] : 0;   // tail -> padding row 0
        idxC[k] = (ki < LH) ? ch[ki] : 0;
    }
    // ctx index for this lane's two output elements (j = lane, lane+32)
    const int cidx0 = cids[lane >> 5];          // for j in [0,32): id (lane>>5)... see below
    // Actually each lane covers j = lane and j = lane + ... handled explicitly:
    // j0 = lane        -> id (lane>>5)    hmm; full loop below uses 10 iterations.

    // ---- phase 1: issue ALL data loads back-to-back ----
    f32x4 vi[NIT], vc[NIT];
    #pragma unroll
    for (int k = 0; k < NIT; ++k) {
        vi[k] = *reinterpret_cast<const f32x4*>(
            W_item + ((size_t)idxI[k] * DI + l16 * 4));
        vc[k] = *reinterpret_cast<const f32x4*>(
            W_cate + ((size_t)idxC[k] * DC + l16 * 4));
    }

    // ctx: 640 floats, 10 per lane (j = lane + 64*t)
    float cv[10];
    #pragma unroll
    for (int t = 0; t < 10; ++t) {
        const int j = lane + 64 * t;
        const int idx = cids[j >> 5];
        const int d   = j & 31;
        cv[t] = (idx != 0) ? W_ctx[idx * DX + d] : 0.0f;
    }

    const float* __restrict__ dv = dense_vec + (size_t)row * DDENSE;
    const float d0 = dv[lane];
    const float d1 = dv[64 + lane];
    const float pr = price[row];

    // ---- fence: nothing below may be hoisted above / loads sunk below ----
    __builtin_amdgcn_sched_barrier(0);

    // ---- phase 2: arithmetic + stores ----
    f32x4 iacc = {0.f, 0.f, 0.f, 0.f};
    f32x4 cacc = {0.f, 0.f, 0.f, 0.f};
    #pragma unroll
    for (int k = 0; k < NIT; ++k) {
        const float si = (idxI[k] != 0) ? 1.0f : 0.0f;  // padding_idx
        const float sc = (idxC[k] != 0) ? 1.0f : 0.0f;
        iacc += vi[k] * si;
        cacc += vc[k] * sc;
    }

    // combine 4 sub-group partials (lanes l, l+16, l+32, l+48)
    #pragma unroll
    for (int e = 0; e < 4; ++e) {
        float a = iacc[e];
        a += __shfl_xor(a, 16, 64);
        a += __shfl_xor(a, 32, 64);
        iacc[e] = a;
        float c = cacc[e];
        c += __shfl_xor(c, 16, 64);
        c += __shfl_xor(c, 32, 64);
        cacc[e] = c;
    }

    if (sub == 0) {
        *reinterpret_cast<f32x4*>(orow + l16 * 4) = iacc;
        const float inv = 1.0f / (float)LH;  // mean divides by L incl. padding
        cacc *= inv;
        *reinterpret_cast<f32x4*>(orow + DI + l16 * 4) = cacc;
    }

    #pragma unroll
    for (int t = 0; t < 10; ++t) {
        orow[DI + DC + lane + 64 * t] = cv[t];
    }

    if (lane == 0) orow[DI + DC + LC * DX] = pr;
    orow[DI + DC + LC * DX + 1 + lane]      = d0;
    orow[DI + DC + LC * DX + 1 + 64 + lane] = d1;
    (void)cidx0;
}

extern "C" void kernel_launch(void* const* d_in, const int* in_sizes, int n_in,
                              void* d_out, int out_size, void* d_ws, size_t ws_size,
                              hipStream_t stream) {
    const int*   item_hist = (const int*)  d_in[0];
    const int*   cate_hist = (const int*)  d_in[1];
    const int*   ctx_ids   = (const int*)  d_in[2];
    const float* price     = (const float*)d_in[3];
    const float* dense_vec = (const float*)d_in[4];
    const float* W_item    = (const float*)d_in[5];
    const float* W_cate    = (const float*)d_in[6];
    const float* W_ctx     = (const float*)d_in[7];
    float* out = (float*)d_out;

    const int B = in_sizes[0] / LH;         // 16384
    const int grid = (B + 3) / 4;           // 4 rows per 256-thread block
    featlayer_kernel<<<grid, 256, 0, stream>>>(
        item_hist, cate_hist, ctx_ids, price, dense_vec,
        W_item, W_cate, W_ctx, out, B);
}

// Round 6
// 71.700 us; speedup vs baseline: 1.1574x; 1.1574x over previous
//
#include <hip/hip_runtime.h>

// FeatureLayer: out[row] = concat( sum_k W_item[item_hist[row,k]],        (64)
//                                  mean_k W_cate[cate_hist[row,k]],       (64)
//                                  concat_k W_ctx[ctx_ids[row,k]],        (640)
//                                  price[row],                            (1)
//                                  dense_vec[row] )                       (128)
// padding_idx = 0: index 0 contributes zeros. Mean divides by L=50 incl. padding.
//
// R5 theory: VMEM-instruction-rate bound (flat 76-85us across occupancy/MLP
// configs). Minimize VMEM instruction count at equal bytes:
//   - indices: 3 coalesced block loads -> LDS (was 52 broadcast loads/wave)
//   - ctx: 3 float4 loads/wave (was 10 scalar)
//   - output: stage block's 4 rows in LDS (3588 floats == 897 float4,
//     block-aligned), store with 16 dwordx4 per block (was ~60 scalar instrs)

#define LH 50      // item/cate history length
#define LC 20      // ctx length
#define DI 64      // item emb dim
#define DC 64      // cate emb dim
#define DX 32      // ctx emb dim
#define DDENSE 128
#define OUT_D 897  // 64 + 64 + 640 + 1 + 128
#define NIT 13     // ceil(LH/4)
#define ROWS 4     // rows per 256-thread block
#define BLK_OUT (ROWS * OUT_D)   // 3588 floats = 897 float4 exactly

typedef float f32x4 __attribute__((ext_vector_type(4)));

__global__ __launch_bounds__(256) void featlayer_kernel(
    const int* __restrict__ item_hist,
    const int* __restrict__ cate_hist,
    const int* __restrict__ ctx_ids,
    const float* __restrict__ price,
    const float* __restrict__ dense_vec,
    const float* __restrict__ W_item,
    const float* __restrict__ W_cate,
    const float* __restrict__ W_ctx,
    float* __restrict__ out,
    int B)
{
    __shared__ __align__(16) float obuf[BLK_OUT];   // block's output image
    __shared__ int ih_s[ROWS * LH];                 // 200
    __shared__ int ch_s[ROWS * LH];                 // 200
    __shared__ int cx_s[ROWS * LC];                 // 80

    const int t     = threadIdx.x;
    const int rbase = blockIdx.x * ROWS;

    // ---- stage all indices with 3 coalesced loads ----
    if (t < ROWS * LH) {
        ih_s[t] = item_hist[(size_t)rbase * LH + t];
        ch_s[t] = cate_hist[(size_t)rbase * LH + t];
    }
    if (t < ROWS * LC) cx_s[t] = ctx_ids[(size_t)rbase * LC + t];

    // ---- dense: 512 floats = 128 float4, threads 0..127, into LDS ----
    if (t < 128) {
        const int r = t >> 5;          // row 0..3
        const int c = t & 31;          // float4 chunk within row
        const f32x4 dvv = *reinterpret_cast<const f32x4*>(
            dense_vec + ((size_t)(rbase + r) * DDENSE + c * 4));
        float* o = obuf + r * OUT_D + (DI + DC + LC * DX + 1) + c * 4;
        o[0] = dvv.x; o[1] = dvv.y; o[2] = dvv.z; o[3] = dvv.w;
    }
    if (t < ROWS) obuf[t * OUT_D + DI + DC + LC * DX] = price[rbase + t];

    __syncthreads();   // indices visible to all waves

    const int w    = t >> 6;     // wave = local row
    const int lane = t & 63;
    const int sub  = lane >> 4;  // 0..3
    const int l16  = lane & 15;  // 0..15

    // ---- this wave's indices from LDS (broadcast reads, cheap) ----
    int idxI[NIT], idxC[NIT];
    #pragma unroll
    for (int k = 0; k < NIT; ++k) {
        const int ki = sub + 4 * k;
        idxI[k] = (ki < LH) ? ih_s[w * LH + ki] : 0;
        idxC[k] = (ki < LH) ? ch_s[w * LH + ki] : 0;
    }

    // ---- item + cate gathers (26 dwordx4 per wave, irreducible) ----
    f32x4 iacc = {0.f, 0.f, 0.f, 0.f};
    f32x4 cacc = {0.f, 0.f, 0.f, 0.f};
    #pragma unroll
    for (int k = 0; k < NIT; ++k) {
        const f32x4 vi = *reinterpret_cast<const f32x4*>(
            W_item + ((size_t)idxI[k] * DI + l16 * 4));
        const f32x4 vc = *reinterpret_cast<const f32x4*>(
            W_cate + ((size_t)idxC[k] * DC + l16 * 4));
        const float si = (idxI[k] != 0) ? 1.0f : 0.0f;  // padding_idx
        const float sc = (idxC[k] != 0) ? 1.0f : 0.0f;
        iacc += vi * si;
        cacc += vc * sc;
    }

    // combine 4 sub-group partials (lanes l, l+16, l+32, l+48)
    #pragma unroll
    for (int e = 0; e < 4; ++e) {
        float a = iacc[e];
        a += __shfl_xor(a, 16, 64);
        a += __shfl_xor(a, 32, 64);
        iacc[e] = a;
        float c = cacc[e];
        c += __shfl_xor(c, 16, 64);
        c += __shfl_xor(c, 32, 64);
        cacc[e] = c;
    }

    if (sub == 0) {
        float* oi = obuf + w * OUT_D + l16 * 4;
        float* oc = obuf + w * OUT_D + DI + l16 * 4;
        const float inv = 1.0f / (float)LH;  // mean divides by L incl. padding
        #pragma unroll
        for (int e = 0; e < 4; ++e) {
            oi[e] = iacc[e];
            oc[e] = cacc[e] * inv;
        }
    }

    // ---- ctx: 160 float4 chunks per row; lane handles chunks lane,+64,+128 ----
    #pragma unroll
    for (int t2 = 0; t2 < 3; ++t2) {
        const int c = lane + 64 * t2;
        if (c < (LC * DX) / 4) {               // 160 chunks
            const int id = cx_s[w * LC + (c >> 3)];   // 8 chunks per ctx id
            f32x4 v = {0.f, 0.f, 0.f, 0.f};
            if (id != 0)
                v = *reinterpret_cast<const f32x4*>(
                    W_ctx + ((size_t)id * DX + (c & 7) * 4));
            float* o = obuf + w * OUT_D + DI + DC + 4 * c;
            o[0] = v.x; o[1] = v.y; o[2] = v.z; o[3] = v.w;
        }
    }

    __syncthreads();   // block output image complete

    // ---- store: 897 float4, contiguous, 16B-aligned (block base % 16 == 0) ----
    float* __restrict__ oblk = out + (size_t)rbase * OUT_D;
    #pragma unroll
    for (int i = 0; i < 4; ++i) {
        const int c = t + 256 * i;
        if (c < BLK_OUT / 4) {
            const f32x4 v = *reinterpret_cast<const f32x4*>(obuf + 4 * c);
            *reinterpret_cast<f32x4*>(oblk + 4 * c) = v;
        }
    }
}

extern "C" void kernel_launch(void* const* d_in, const int* in_sizes, int n_in,
                              void* d_out, int out_size, void* d_ws, size_t ws_size,
                              hipStream_t stream) {
    const int*   item_hist = (const int*)  d_in[0];
    const int*   cate_hist = (const int*)  d_in[1];
    const int*   ctx_ids   = (const int*)  d_in[2];
    const float* price     = (const float*)d_in[3];
    const float* dense_vec = (const float*)d_in[4];
    const float* W_item    = (const float*)d_in[5];
    const float* W_cate    = (const float*)d_in[6];
    const float* W_ctx     = (const float*)d_in[7];
    float* out = (float*)d_out;

    const int B = in_sizes[0] / LH;         // 16384 (multiple of ROWS)
    const int grid = (B + ROWS - 1) / ROWS;
    featlayer_kernel<<<grid, 256, 0, stream>>>(
        item_hist, cate_hist, ctx_ids, price, dense_vec,
        W_item, W_cate, W_ctx, out, B);
}

// Round 7
// 58.358 us; speedup vs baseline: 1.4220x; 1.2286x over previous
//
#include <hip/hip_runtime.h>

// FeatureLayer: out[row] = concat( sum_k W_item[item_hist[row,k]],        (64)
//                                  mean_k W_cate[cate_hist[row,k]],       (64)
//                                  concat_k W_ctx[ctx_ids[row,k]],        (640)
//                                  price[row],                            (1)
//                                  dense_vec[row] )                       (128)
// padding_idx = 0: index 0 contributes zeros. Mean divides by L=50 incl. padding.
//
// R6 theory: random-granule HBM-bytes bound (~3.7 TB/s effective, FETCH flat
// at ~200 MB across all schedules). Lever: gather fewer bytes. Pre-pass
// converts both 64-dim fp32 tables to fp16 in d_ws (streaming, efficient);
// main kernel gathers 128 B/row instead of 256 B. fp16 noise ~0.01-0.05
// absmax on sums of 50 — far under the 0.73 threshold.

#define LH 50      // item/cate history length
#define LC 20      // ctx length
#define DI 64      // item emb dim
#define DC 64      // cate emb dim
#define DX 32      // ctx emb dim
#define DDENSE 128
#define OUT_D 897  // 64 + 64 + 640 + 1 + 128
#define ROWS 4     // rows per 256-thread block
#define BLK_OUT (ROWS * OUT_D)   // 3588 floats = 897 float4 exactly
#define NROW_TAB 100000
#define TAB_ELEMS (NROW_TAB * 64)        // 6.4M floats per table
#define NIT8 7     // ceil(LH/8)

typedef float    f32x4 __attribute__((ext_vector_type(4)));
typedef _Float16 f16x4 __attribute__((ext_vector_type(4)));
typedef _Float16 f16x8 __attribute__((ext_vector_type(8)));

// ---------------- pre-pass: fp32 tables -> fp16 in workspace ----------------
__global__ __launch_bounds__(256) void convert_tables_kernel(
    const float* __restrict__ Wi, const float* __restrict__ Wc,
    _Float16* __restrict__ Hi, _Float16* __restrict__ Hc)
{
    const int stride = gridDim.x * blockDim.x;
    for (int i = blockIdx.x * blockDim.x + threadIdx.x;
         i < TAB_ELEMS / 4; i += stride) {
        const f32x4 a = reinterpret_cast<const f32x4*>(Wi)[i];
        const f32x4 b = reinterpret_cast<const f32x4*>(Wc)[i];
        f16x4 ha, hb;
        #pragma unroll
        for (int e = 0; e < 4; ++e) { ha[e] = (_Float16)a[e]; hb[e] = (_Float16)b[e]; }
        reinterpret_cast<f16x4*>(Hi)[i] = ha;
        reinterpret_cast<f16x4*>(Hc)[i] = hb;
    }
}

// ---------------- main kernel (templated on fp16-gather path) ----------------
template <bool HALF>
__global__ __launch_bounds__(256) void featlayer_kernel(
    const int* __restrict__ item_hist,
    const int* __restrict__ cate_hist,
    const int* __restrict__ ctx_ids,
    const float* __restrict__ price,
    const float* __restrict__ dense_vec,
    const float* __restrict__ W_item,
    const float* __restrict__ W_cate,
    const _Float16* __restrict__ H_item,
    const _Float16* __restrict__ H_cate,
    const float* __restrict__ W_ctx,
    float* __restrict__ out,
    int B)
{
    __shared__ __align__(16) float obuf[BLK_OUT];   // block's output image
    __shared__ int ih_s[ROWS * LH];
    __shared__ int ch_s[ROWS * LH];
    __shared__ int cx_s[ROWS * LC];

    const int t     = threadIdx.x;
    const int rbase = blockIdx.x * ROWS;

    // ---- stage all indices with 3 coalesced loads ----
    if (t < ROWS * LH) {
        ih_s[t] = item_hist[(size_t)rbase * LH + t];
        ch_s[t] = cate_hist[(size_t)rbase * LH + t];
    }
    if (t < ROWS * LC) cx_s[t] = ctx_ids[(size_t)rbase * LC + t];

    // ---- dense: 512 floats = 128 float4, threads 0..127, into LDS ----
    if (t < 128) {
        const int r = t >> 5;
        const int c = t & 31;
        const f32x4 dvv = *reinterpret_cast<const f32x4*>(
            dense_vec + ((size_t)(rbase + r) * DDENSE + c * 4));
        float* o = obuf + r * OUT_D + (DI + DC + LC * DX + 1) + c * 4;
        o[0] = dvv.x; o[1] = dvv.y; o[2] = dvv.z; o[3] = dvv.w;
    }
    if (t < ROWS) obuf[t * OUT_D + DI + DC + LC * DX] = price[rbase + t];

    __syncthreads();

    const int w    = t >> 6;     // wave = local row
    const int lane = t & 63;

    if (HALF) {
        // 8 lanes per table row (f16x8 = 16B per lane), 8 rows in flight/instr
        const int sub8 = lane >> 3;   // 0..7: which index within a group of 8
        const int l8   = lane & 7;    // 0..7: which f16x8 of the 64-dim row

        int idxI[NIT8], idxC[NIT8];
        #pragma unroll
        for (int k = 0; k < NIT8; ++k) {
            const int ki = sub8 + 8 * k;
            idxI[k] = (ki < LH) ? ih_s[w * LH + ki] : 0;
            idxC[k] = (ki < LH) ? ch_s[w * LH + ki] : 0;
        }

        float iacc[8] = {0,0,0,0,0,0,0,0};
        float cacc[8] = {0,0,0,0,0,0,0,0};
        #pragma unroll
        for (int k = 0; k < NIT8; ++k) {
            const f16x8 vi = *reinterpret_cast<const f16x8*>(
                H_item + ((size_t)idxI[k] * 64 + l8 * 8));
            const f16x8 vc = *reinterpret_cast<const f16x8*>(
                H_cate + ((size_t)idxC[k] * 64 + l8 * 8));
            const float si = (idxI[k] != 0) ? 1.0f : 0.0f;  // padding_idx
            const float sc = (idxC[k] != 0) ? 1.0f : 0.0f;
            #pragma unroll
            for (int e = 0; e < 8; ++e) {
                iacc[e] += (float)vi[e] * si;
                cacc[e] += (float)vc[e] * sc;
            }
        }

        // combine 8 sub-group partials (lanes l, l+8, ..., l+56)
        #pragma unroll
        for (int e = 0; e < 8; ++e) {
            float a = iacc[e];
            a += __shfl_xor(a, 8, 64);
            a += __shfl_xor(a, 16, 64);
            a += __shfl_xor(a, 32, 64);
            iacc[e] = a;
            float c = cacc[e];
            c += __shfl_xor(c, 8, 64);
            c += __shfl_xor(c, 16, 64);
            c += __shfl_xor(c, 32, 64);
            cacc[e] = c;
        }

        if (sub8 == 0) {   // lanes 0..7, lane l8 owns dims [l8*8, l8*8+8)
            float* oi = obuf + w * OUT_D + l8 * 8;
            float* oc = obuf + w * OUT_D + DI + l8 * 8;
            const float inv = 1.0f / (float)LH;
            #pragma unroll
            for (int e = 0; e < 8; ++e) {
                oi[e] = iacc[e];
                oc[e] = cacc[e] * inv;
            }
        }
    } else {
        // fp32 fallback: 16 lanes per row (f32x4 per lane)
        const int sub = lane >> 4;
        const int l16 = lane & 15;
        int idxI[13], idxC[13];
        #pragma unroll
        for (int k = 0; k < 13; ++k) {
            const int ki = sub + 4 * k;
            idxI[k] = (ki < LH) ? ih_s[w * LH + ki] : 0;
            idxC[k] = (ki < LH) ? ch_s[w * LH + ki] : 0;
        }
        f32x4 iacc = {0,0,0,0}, cacc = {0,0,0,0};
        #pragma unroll
        for (int k = 0; k < 13; ++k) {
            const f32x4 vi = *reinterpret_cast<const f32x4*>(
                W_item + ((size_t)idxI[k] * DI + l16 * 4));
            const f32x4 vc = *reinterpret_cast<const f32x4*>(
                W_cate + ((size_t)idxC[k] * DC + l16 * 4));
            iacc += vi * ((idxI[k] != 0) ? 1.0f : 0.0f);
            cacc += vc * ((idxC[k] != 0) ? 1.0f : 0.0f);
        }
        #pragma unroll
        for (int e = 0; e < 4; ++e) {
            float a = iacc[e];
            a += __shfl_xor(a, 16, 64); a += __shfl_xor(a, 32, 64);
            iacc[e] = a;
            float c = cacc[e];
            c += __shfl_xor(c, 16, 64); c += __shfl_xor(c, 32, 64);
            cacc[e] = c;
        }
        if (sub == 0) {
            float* oi = obuf + w * OUT_D + l16 * 4;
            float* oc = obuf + w * OUT_D + DI + l16 * 4;
            const float inv = 1.0f / (float)LH;
            #pragma unroll
            for (int e = 0; e < 4; ++e) { oi[e] = iacc[e]; oc[e] = cacc[e] * inv; }
        }
    }

    // ---- ctx: 160 float4 chunks per row; lane handles chunks lane,+64,+128 ----
    #pragma unroll
    for (int t2 = 0; t2 < 3; ++t2) {
        const int c = lane + 64 * t2;
        if (c < (LC * DX) / 4) {
            const int id = cx_s[w * LC + (c >> 3)];
            f32x4 v = {0.f, 0.f, 0.f, 0.f};
            if (id != 0)
                v = *reinterpret_cast<const f32x4*>(
                    W_ctx + ((size_t)id * DX + (c & 7) * 4));
            float* o = obuf + w * OUT_D + DI + DC + 4 * c;
            o[0] = v.x; o[1] = v.y; o[2] = v.z; o[3] = v.w;
        }
    }

    __syncthreads();

    // ---- store: 897 float4 per block, contiguous, 16B-aligned ----
    float* __restrict__ oblk = out + (size_t)rbase * OUT_D;
    #pragma unroll
    for (int i = 0; i < 4; ++i) {
        const int c = t + 256 * i;
        if (c < BLK_OUT / 4) {
            const f32x4 v = *reinterpret_cast<const f32x4*>(obuf + 4 * c);
            *reinterpret_cast<f32x4*>(oblk + 4 * c) = v;
        }
    }
}

extern "C" void kernel_launch(void* const* d_in, const int* in_sizes, int n_in,
                              void* d_out, int out_size, void* d_ws, size_t ws_size,
                              hipStream_t stream) {
    const int*   item_hist = (const int*)  d_in[0];
    const int*   cate_hist = (const int*)  d_in[1];
    const int*   ctx_ids   = (const int*)  d_in[2];
    const float* price     = (const float*)d_in[3];
    const float* dense_vec = (const float*)d_in[4];
    const float* W_item    = (const float*)d_in[5];
    const float* W_cate    = (const float*)d_in[6];
    const float* W_ctx     = (const float*)d_in[7];
    float* out = (float*)d_out;

    const int B = in_sizes[0] / LH;         // 16384 (multiple of ROWS)
    const int grid = (B + ROWS - 1) / ROWS;

    const size_t tab_bytes = (size_t)TAB_ELEMS * sizeof(_Float16);  // 12.8 MB
    if (ws_size >= 2 * tab_bytes) {
        _Float16* Hi = (_Float16*)d_ws;
        _Float16* Hc = Hi + TAB_ELEMS;
        convert_tables_kernel<<<2048, 256, 0, stream>>>(W_item, W_cate, Hi, Hc);
        featlayer_kernel<true><<<grid, 256, 0, stream>>>(
            item_hist, cate_hist, ctx_ids, price, dense_vec,
            W_item, W_cate, Hi, Hc, W_ctx, out, B);
    } else {
        featlayer_kernel<false><<<grid, 256, 0, stream>>>(
            item_hist, cate_hist, ctx_ids, price, dense_vec,
            W_item, W_cate, nullptr, nullptr, W_ctx, out, B);
    }
}